// Round 1
// baseline (2062.633 us; speedup 1.0000x reference)
//
#include <hip/hip_runtime.h>

#define KS 5
#define NCH 32
#define IMH 256
#define IMW 256
#define TW 32
#define TH 8
#define HALO_W (TW + 4)
#define HALO_H (TH + 4)
#define CHUNK 8
#define NCHUNK (NCH / CHUNK)
#define TILE_ELEMS (CHUNK * HALO_H * HALO_W)

__device__ __forceinline__ float sigmoidf_(float x) {
    return 1.0f / (1.0f + __expf(-x));
}

__global__ __launch_bounds__(256) void cika_fused(
    const float* __restrict__ lower, const float* __restrict__ upper,
    const float* __restrict__ kca_dw_w, const float* __restrict__ kca_dw_b,
    const float* __restrict__ kca_m1_w, const float* __restrict__ kca_m1_b,
    const float* __restrict__ kca_m2_w, const float* __restrict__ kca_m2_b,
    const float* __restrict__ ksa_dw_w, const float* __restrict__ ksa_dw_b,
    const float* __restrict__ ksa_m1_w, const float* __restrict__ ksa_m1_b,
    const float* __restrict__ ksa_m2_w, const float* __restrict__ ksa_m2_b,
    const float* __restrict__ low_dyn_w, const float* __restrict__ low_dyn_b,
    const float* __restrict__ low_pw_w, const float* __restrict__ low_pw_b,
    const float* __restrict__ up_dw_w, const float* __restrict__ up_dw_b,
    const float* __restrict__ up_pw_w, const float* __restrict__ up_pw_b,
    float* __restrict__ out_low, float* __restrict__ out_up)
{
    __shared__ float tile[TILE_ELEMS];

    const int tid = threadIdx.x;
    const int tx = tid & (TW - 1);
    const int ty = tid >> 5;
    const int tile_x = blockIdx.x * TW;
    const int tile_y = blockIdx.y * TH;
    const int n = blockIdx.z;
    const int HW = IMH * IMW;

    const float* lob = lower + (size_t)n * NCH * HW;
    const float* upb = upper + (size_t)n * NCH * HW;

    float dwu_ksa[NCH], dwu_up[NCH];

    // ---------- Phase 1: upper depthwise (ksa_dw and up_dw share window reads) ----------
    #pragma unroll
    for (int ck = 0; ck < NCHUNK; ++ck) {
        const int c0 = ck * CHUNK;
        __syncthreads();
        for (int idx = tid; idx < TILE_ELEMS; idx += 256) {
            int c = idx / (HALO_H * HALO_W);
            int r = idx - c * (HALO_H * HALO_W);
            int hy = r / HALO_W, hx = r - hy * HALO_W;
            int gy = tile_y + hy - 2, gx = tile_x + hx - 2;
            float v = 0.0f;
            if (gy >= 0 && gy < IMH && gx >= 0 && gx < IMW)
                v = upb[(size_t)(c0 + c) * HW + gy * IMW + gx];
            tile[idx] = v;
        }
        __syncthreads();
        #pragma unroll
        for (int cc = 0; cc < CHUNK; ++cc) {
            const int c = c0 + cc;
            float ak = ksa_dw_b[c];
            float au = up_dw_b[c];
            const float* tp = tile + cc * (HALO_H * HALO_W) + ty * HALO_W + tx;
            #pragma unroll
            for (int i = 0; i < KS; ++i)
                #pragma unroll
                for (int j = 0; j < KS; ++j) {
                    float wv = tp[i * HALO_W + j];
                    ak = fmaf(wv, ksa_dw_w[c * 25 + i * KS + j], ak);
                    au = fmaf(wv, up_dw_w[c * 25 + i * KS + j], au);
                }
            dwu_ksa[c] = ak;
            dwu_up[c]  = au;
        }
    }

    // ---------- Phase 2: KSA MLP -> ksa[25] (streamed hidden, 50 units) ----------
    #pragma unroll
    for (int c = 0; c < NCH; ++c) dwu_ksa[c] = fmaxf(dwu_ksa[c], 0.0f);
    float ksa[25];
    #pragma unroll
    for (int k = 0; k < 25; ++k) ksa[k] = ksa_m2_b[k];
    for (int h = 0; h < 50; ++h) {
        float hv = ksa_m1_b[h];
        #pragma unroll
        for (int c = 0; c < NCH; ++c)
            hv = fmaf(ksa_m1_w[h * NCH + c], dwu_ksa[c], hv);
        hv = fmaxf(hv, 0.0f);
        #pragma unroll
        for (int k = 0; k < 25; ++k)
            ksa[k] = fmaf(ksa_m2_w[k * 50 + h], hv, ksa[k]);
    }
    #pragma unroll
    for (int k = 0; k < 25; ++k) ksa[k] = sigmoidf_(ksa[k]);

    // ---------- Phase 3: lower pass — kca-dw + dynamic-dw + low pointwise, one window read ----------
    float dwl[NCH];
    float low_acc[NCH];
    #pragma unroll
    for (int o = 0; o < NCH; ++o) low_acc[o] = 0.0f;
    #pragma unroll
    for (int ck = 0; ck < NCHUNK; ++ck) {
        const int c0 = ck * CHUNK;
        __syncthreads();
        for (int idx = tid; idx < TILE_ELEMS; idx += 256) {
            int c = idx / (HALO_H * HALO_W);
            int r = idx - c * (HALO_H * HALO_W);
            int hy = r / HALO_W, hx = r - hy * HALO_W;
            int gy = tile_y + hy - 2, gx = tile_x + hx - 2;
            float v = 0.0f;
            if (gy >= 0 && gy < IMH && gx >= 0 && gx < IMW)
                v = lob[(size_t)(c0 + c) * HW + gy * IMW + gx];
            tile[idx] = v;
        }
        __syncthreads();
        #pragma unroll
        for (int cc = 0; cc < CHUNK; ++cc) {
            const int c = c0 + cc;
            float ad = kca_dw_b[c];
            float td = low_dyn_b[c];
            const float* tp = tile + cc * (HALO_H * HALO_W) + ty * HALO_W + tx;
            #pragma unroll
            for (int i = 0; i < KS; ++i)
                #pragma unroll
                for (int j = 0; j < KS; ++j) {
                    float wv = tp[i * HALO_W + j];
                    ad = fmaf(wv, kca_dw_w[c * 25 + i * KS + j], ad);
                    td = fmaf(wv * low_dyn_w[c * 25 + i * KS + j], ksa[i * KS + j], td);
                }
            dwl[c] = ad;
            #pragma unroll
            for (int o = 0; o < NCH; ++o)
                low_acc[o] = fmaf(low_pw_w[o * NCH + c], td, low_acc[o]);
        }
    }

    // ---------- Phase 4: KCA MLP -> kca[32] ----------
    #pragma unroll
    for (int c = 0; c < NCH; ++c) dwl[c] = fmaxf(dwl[c], 0.0f);
    float kca[NCH];
    #pragma unroll
    for (int k = 0; k < NCH; ++k) kca[k] = kca_m2_b[k];
    #pragma unroll
    for (int h = 0; h < 8; ++h) {
        float hv = kca_m1_b[h];
        #pragma unroll
        for (int c = 0; c < NCH; ++c)
            hv = fmaf(kca_m1_w[h * NCH + c], dwl[c], hv);
        hv = fmaxf(hv, 0.0f);
        #pragma unroll
        for (int k = 0; k < NCH; ++k)
            kca[k] = fmaf(kca_m2_w[k * 8 + h], hv, kca[k]);
    }
    #pragma unroll
    for (int k = 0; k < NCH; ++k) kca[k] = sigmoidf_(kca[k]);

    // ---------- Phase 5: up path — gate by kca, pointwise ----------
    float up_acc[NCH];
    #pragma unroll
    for (int o = 0; o < NCH; ++o) up_acc[o] = 0.0f;
    #pragma unroll
    for (int c = 0; c < NCH; ++c) {
        float t2 = dwu_up[c] * kca[c];
        #pragma unroll
        for (int o = 0; o < NCH; ++o)
            up_acc[o] = fmaf(up_pw_w[o * NCH + c], t2, up_acc[o]);
    }

    // ---------- Phase 6: store ----------
    const int x = tile_x + tx, y = tile_y + ty;
    float* ol = out_low + (size_t)n * NCH * HW + y * IMW + x;
    float* ou = out_up  + (size_t)n * NCH * HW + y * IMW + x;
    #pragma unroll
    for (int o = 0; o < NCH; ++o) {
        ol[(size_t)o * HW] = low_acc[o] + low_pw_b[o];
        ou[(size_t)o * HW] = up_acc[o]  + up_pw_b[o];
    }
}

extern "C" void kernel_launch(void* const* d_in, const int* in_sizes, int n_in,
                              void* d_out, int out_size, void* d_ws, size_t ws_size,
                              hipStream_t stream) {
    const float* lower    = (const float*)d_in[0];
    const float* upper    = (const float*)d_in[1];
    const float* kca_dw_w = (const float*)d_in[2];
    const float* kca_dw_b = (const float*)d_in[3];
    const float* kca_m1_w = (const float*)d_in[4];
    const float* kca_m1_b = (const float*)d_in[5];
    const float* kca_m2_w = (const float*)d_in[6];
    const float* kca_m2_b = (const float*)d_in[7];
    const float* ksa_dw_w = (const float*)d_in[8];
    const float* ksa_dw_b = (const float*)d_in[9];
    const float* ksa_m1_w = (const float*)d_in[10];
    const float* ksa_m1_b = (const float*)d_in[11];
    const float* ksa_m2_w = (const float*)d_in[12];
    const float* ksa_m2_b = (const float*)d_in[13];
    const float* low_dyn_w = (const float*)d_in[14];
    const float* low_dyn_b = (const float*)d_in[15];
    const float* low_pw_w  = (const float*)d_in[16];
    const float* low_pw_b  = (const float*)d_in[17];
    const float* up_dw_w   = (const float*)d_in[18];
    const float* up_dw_b   = (const float*)d_in[19];
    const float* up_pw_w   = (const float*)d_in[20];
    const float* up_pw_b   = (const float*)d_in[21];

    const int N = in_sizes[0] / (NCH * IMH * IMW);
    float* out_low = (float*)d_out;
    float* out_up  = (float*)d_out + (size_t)N * NCH * IMH * IMW;

    dim3 grid(IMW / TW, IMH / TH, N);
    cika_fused<<<grid, dim3(256), 0, stream>>>(
        lower, upper,
        kca_dw_w, kca_dw_b, kca_m1_w, kca_m1_b, kca_m2_w, kca_m2_b,
        ksa_dw_w, ksa_dw_b, ksa_m1_w, ksa_m1_b, ksa_m2_w, ksa_m2_b,
        low_dyn_w, low_dyn_b, low_pw_w, low_pw_b,
        up_dw_w, up_dw_b, up_pw_w, up_pw_b,
        out_low, out_up);
}

// Round 2
// 709.047 us; speedup vs baseline: 2.9090x; 2.9090x over previous
//
#include <hip/hip_runtime.h>

#define KS 5
#define NCH 32
#define IMH 256
#define IMW 256
#define TW 32
#define TH 8
#define HALO_W (TW + 4)
#define HALO_H (TH + 4)
#define CHUNK 8
#define NCHUNK (NCH / CHUNK)
#define TILE_ELEMS (CHUNK * HALO_H * HALO_W)
#define HW (IMH * IMW)

__device__ __forceinline__ float sigmoidf_(float x) {
    return 1.0f / (1.0f + __expf(-x));
}

// ---------------------------------------------------------------------------
// Kernel A: upper path. Computes dwu_up (stored to ws immediately, per-chunk)
// and ksa attention maps (sigmoid, stored to ws).
// Peak per-thread live state ~70 floats.
// ---------------------------------------------------------------------------
__global__ __launch_bounds__(256) void cika_ksa_kernel(
    const float* __restrict__ upper,
    const float* __restrict__ ksa_dw_w, const float* __restrict__ ksa_dw_b,
    const float* __restrict__ ksa_m1_w, const float* __restrict__ ksa_m1_b,
    const float* __restrict__ ksa_m2_w, const float* __restrict__ ksa_m2_b,
    const float* __restrict__ up_dw_w, const float* __restrict__ up_dw_b,
    float* __restrict__ ws_dwu,   // (N, 32, H, W)
    float* __restrict__ ws_ksa)   // (N, 25, H, W)
{
    __shared__ float tile[TILE_ELEMS];

    const int tid = threadIdx.x;
    const int tx = tid & (TW - 1);
    const int ty = tid >> 5;
    const int tile_x = blockIdx.x * TW;
    const int tile_y = blockIdx.y * TH;
    const int n = blockIdx.z;
    const int x = tile_x + tx, y = tile_y + ty;
    const int pix = y * IMW + x;

    const float* upb = upper + (size_t)n * NCH * HW;
    float* dwu_out = ws_dwu + (size_t)n * NCH * HW + pix;

    float dwu_ksa[NCH];

    #pragma unroll
    for (int ck = 0; ck < NCHUNK; ++ck) {
        const int c0 = ck * CHUNK;
        __syncthreads();
        for (int idx = tid; idx < TILE_ELEMS; idx += 256) {
            int c = idx / (HALO_H * HALO_W);
            int r = idx - c * (HALO_H * HALO_W);
            int hy = r / HALO_W, hx = r - hy * HALO_W;
            int gy = tile_y + hy - 2, gx = tile_x + hx - 2;
            float v = 0.0f;
            if (gy >= 0 && gy < IMH && gx >= 0 && gx < IMW)
                v = upb[(size_t)(c0 + c) * HW + gy * IMW + gx];
            tile[idx] = v;
        }
        __syncthreads();
        #pragma unroll
        for (int cc = 0; cc < CHUNK; ++cc) {
            const int c = c0 + cc;
            float ak = ksa_dw_b[c];
            float au = up_dw_b[c];
            const float* tp = tile + cc * (HALO_H * HALO_W) + ty * HALO_W + tx;
            #pragma unroll
            for (int i = 0; i < KS; ++i)
                #pragma unroll
                for (int j = 0; j < KS; ++j) {
                    float wv = tp[i * HALO_W + j];
                    ak = fmaf(wv, ksa_dw_w[c * 25 + i * KS + j], ak);
                    au = fmaf(wv, up_dw_w[c * 25 + i * KS + j], au);
                }
            dwu_ksa[c] = fmaxf(ak, 0.0f);
            dwu_out[(size_t)c * HW] = au;   // store immediately: never 32 live
        }
    }

    // KSA MLP: 32 -> 50 (relu) -> 25 (sigmoid), hidden streamed
    float ksa[25];
    #pragma unroll
    for (int k = 0; k < 25; ++k) ksa[k] = ksa_m2_b[k];
    for (int h = 0; h < 50; ++h) {
        float hv = ksa_m1_b[h];
        #pragma unroll
        for (int c = 0; c < NCH; ++c)
            hv = fmaf(ksa_m1_w[h * NCH + c], dwu_ksa[c], hv);
        hv = fmaxf(hv, 0.0f);
        #pragma unroll
        for (int k = 0; k < 25; ++k)
            ksa[k] = fmaf(ksa_m2_w[k * 50 + h], hv, ksa[k]);
    }

    float* ksa_out = ws_ksa + (size_t)n * 25 * HW + pix;
    #pragma unroll
    for (int k = 0; k < 25; ++k)
        ksa_out[(size_t)k * HW] = sigmoidf_(ksa[k]);
}

// ---------------------------------------------------------------------------
// Kernel B: lower path + both outputs.
// Phase 1: ksa[25] from ws. Phase 2: lower tiles -> dwl[32] (kca-dw) and
// dynamic-dw 'td' streamed into low_acc[32]. Store out_low (frees low_acc).
// Phase 3: KCA MLP -> kca[32] (dwl dies). Phase 4: stream dwu_up from ws
// into up-pointwise. Peak live ~120 floats.
// ---------------------------------------------------------------------------
__global__ __launch_bounds__(256) void cika_low_up_kernel(
    const float* __restrict__ lower,
    const float* __restrict__ ws_ksa, const float* __restrict__ ws_dwu,
    const float* __restrict__ kca_dw_w, const float* __restrict__ kca_dw_b,
    const float* __restrict__ kca_m1_w, const float* __restrict__ kca_m1_b,
    const float* __restrict__ kca_m2_w, const float* __restrict__ kca_m2_b,
    const float* __restrict__ low_dyn_w, const float* __restrict__ low_dyn_b,
    const float* __restrict__ low_pw_w, const float* __restrict__ low_pw_b,
    const float* __restrict__ up_pw_w, const float* __restrict__ up_pw_b,
    float* __restrict__ out_low, float* __restrict__ out_up)
{
    __shared__ float tile[TILE_ELEMS];

    const int tid = threadIdx.x;
    const int tx = tid & (TW - 1);
    const int ty = tid >> 5;
    const int tile_x = blockIdx.x * TW;
    const int tile_y = blockIdx.y * TH;
    const int n = blockIdx.z;
    const int x = tile_x + tx, y = tile_y + ty;
    const int pix = y * IMW + x;

    const float* lob = lower + (size_t)n * NCH * HW;

    // ksa attention weights for this pixel
    float ksa[25];
    {
        const float* kp = ws_ksa + (size_t)n * 25 * HW + pix;
        #pragma unroll
        for (int k = 0; k < 25; ++k) ksa[k] = kp[(size_t)k * HW];
    }

    float dwl[NCH];
    float low_acc[NCH];
    #pragma unroll
    for (int o = 0; o < NCH; ++o) low_acc[o] = 0.0f;

    #pragma unroll
    for (int ck = 0; ck < NCHUNK; ++ck) {
        const int c0 = ck * CHUNK;
        __syncthreads();
        for (int idx = tid; idx < TILE_ELEMS; idx += 256) {
            int c = idx / (HALO_H * HALO_W);
            int r = idx - c * (HALO_H * HALO_W);
            int hy = r / HALO_W, hx = r - hy * HALO_W;
            int gy = tile_y + hy - 2, gx = tile_x + hx - 2;
            float v = 0.0f;
            if (gy >= 0 && gy < IMH && gx >= 0 && gx < IMW)
                v = lob[(size_t)(c0 + c) * HW + gy * IMW + gx];
            tile[idx] = v;
        }
        __syncthreads();
        #pragma unroll
        for (int cc = 0; cc < CHUNK; ++cc) {
            const int c = c0 + cc;
            float ad = kca_dw_b[c];
            float td = low_dyn_b[c];
            const float* tp = tile + cc * (HALO_H * HALO_W) + ty * HALO_W + tx;
            #pragma unroll
            for (int i = 0; i < KS; ++i)
                #pragma unroll
                for (int j = 0; j < KS; ++j) {
                    float wv = tp[i * HALO_W + j];
                    ad = fmaf(wv, kca_dw_w[c * 25 + i * KS + j], ad);
                    td = fmaf(wv * low_dyn_w[c * 25 + i * KS + j], ksa[i * KS + j], td);
                }
            dwl[c] = ad;
            #pragma unroll
            for (int o = 0; o < NCH; ++o)
                low_acc[o] = fmaf(low_pw_w[o * NCH + c], td, low_acc[o]);
        }
    }

    // store out_low now -> frees low_acc
    {
        float* ol = out_low + (size_t)n * NCH * HW + pix;
        #pragma unroll
        for (int o = 0; o < NCH; ++o)
            ol[(size_t)o * HW] = low_acc[o] + low_pw_b[o];
    }

    // KCA MLP: 32 -> 8 (relu) -> 32 (sigmoid)
    #pragma unroll
    for (int c = 0; c < NCH; ++c) dwl[c] = fmaxf(dwl[c], 0.0f);
    float kca[NCH];
    #pragma unroll
    for (int k = 0; k < NCH; ++k) kca[k] = kca_m2_b[k];
    #pragma unroll
    for (int h = 0; h < 8; ++h) {
        float hv = kca_m1_b[h];
        #pragma unroll
        for (int c = 0; c < NCH; ++c)
            hv = fmaf(kca_m1_w[h * NCH + c], dwl[c], hv);
        hv = fmaxf(hv, 0.0f);
        #pragma unroll
        for (int k = 0; k < NCH; ++k)
            kca[k] = fmaf(kca_m2_w[k * 8 + h], hv, kca[k]);
    }
    #pragma unroll
    for (int k = 0; k < NCH; ++k) kca[k] = sigmoidf_(kca[k]);

    // up path: stream dwu_up from ws, gate, pointwise
    float up_acc[NCH];
    #pragma unroll
    for (int o = 0; o < NCH; ++o) up_acc[o] = 0.0f;
    const float* dup = ws_dwu + (size_t)n * NCH * HW + pix;
    #pragma unroll
    for (int c = 0; c < NCH; ++c) {
        float t2 = dup[(size_t)c * HW] * kca[c];
        #pragma unroll
        for (int o = 0; o < NCH; ++o)
            up_acc[o] = fmaf(up_pw_w[o * NCH + c], t2, up_acc[o]);
    }

    float* ou = out_up + (size_t)n * NCH * HW + pix;
    #pragma unroll
    for (int o = 0; o < NCH; ++o)
        ou[(size_t)o * HW] = up_acc[o] + up_pw_b[o];
}

extern "C" void kernel_launch(void* const* d_in, const int* in_sizes, int n_in,
                              void* d_out, int out_size, void* d_ws, size_t ws_size,
                              hipStream_t stream) {
    const float* lower    = (const float*)d_in[0];
    const float* upper    = (const float*)d_in[1];
    const float* kca_dw_w = (const float*)d_in[2];
    const float* kca_dw_b = (const float*)d_in[3];
    const float* kca_m1_w = (const float*)d_in[4];
    const float* kca_m1_b = (const float*)d_in[5];
    const float* kca_m2_w = (const float*)d_in[6];
    const float* kca_m2_b = (const float*)d_in[7];
    const float* ksa_dw_w = (const float*)d_in[8];
    const float* ksa_dw_b = (const float*)d_in[9];
    const float* ksa_m1_w = (const float*)d_in[10];
    const float* ksa_m1_b = (const float*)d_in[11];
    const float* ksa_m2_w = (const float*)d_in[12];
    const float* ksa_m2_b = (const float*)d_in[13];
    const float* low_dyn_w = (const float*)d_in[14];
    const float* low_dyn_b = (const float*)d_in[15];
    const float* low_pw_w  = (const float*)d_in[16];
    const float* low_pw_b  = (const float*)d_in[17];
    const float* up_dw_w   = (const float*)d_in[18];
    const float* up_dw_b   = (const float*)d_in[19];
    const float* up_pw_w   = (const float*)d_in[20];
    const float* up_pw_b   = (const float*)d_in[21];

    const int N = in_sizes[0] / (NCH * HW);
    float* out_low = (float*)d_out;
    float* out_up  = (float*)d_out + (size_t)N * NCH * HW;

    float* ws_dwu = (float*)d_ws;                       // N*32*HW floats
    float* ws_ksa = ws_dwu + (size_t)N * NCH * HW;      // N*25*HW floats

    dim3 grid(IMW / TW, IMH / TH, N);

    cika_ksa_kernel<<<grid, dim3(256), 0, stream>>>(
        upper,
        ksa_dw_w, ksa_dw_b, ksa_m1_w, ksa_m1_b, ksa_m2_w, ksa_m2_b,
        up_dw_w, up_dw_b,
        ws_dwu, ws_ksa);

    cika_low_up_kernel<<<grid, dim3(256), 0, stream>>>(
        lower, ws_ksa, ws_dwu,
        kca_dw_w, kca_dw_b, kca_m1_w, kca_m1_b, kca_m2_w, kca_m2_b,
        low_dyn_w, low_dyn_b, low_pw_w, low_pw_b,
        up_pw_w, up_pw_b,
        out_low, out_up);
}

// Round 3
// 219.200 us; speedup vs baseline: 9.4098x; 3.2347x over previous
//
#include <hip/hip_runtime.h>
#include <hip/hip_bf16.h>

#define KS 5
#define NCH 32
#define IMH 256
#define IMW 256
#define TW 32
#define TH 8
#define HALO_W (TW + 4)
#define HALO_H (TH + 4)
#define CHUNK 8
#define NCHUNK (NCH / CHUNK)
#define TILE_ELEMS (CHUNK * HALO_H * HALO_W)
#define HW (IMH * IMW)
#define OC_CHUNK 8

__device__ __forceinline__ float sigmoidf_(float x) {
    return 1.0f / (1.0f + __expf(-x));
}

// ---------------------------------------------------------------------------
// Kernel A: upper path. dwu_up stored to ws immediately per-channel; KSA MLP
// -> sigmoid ksa maps to ws.
// ---------------------------------------------------------------------------
__global__ __launch_bounds__(256) void cika_ksa_kernel(
    const float* __restrict__ upper,
    const float* __restrict__ ksa_dw_w, const float* __restrict__ ksa_dw_b,
    const float* __restrict__ ksa_m1_w, const float* __restrict__ ksa_m1_b,
    const float* __restrict__ ksa_m2_w, const float* __restrict__ ksa_m2_b,
    const float* __restrict__ up_dw_w, const float* __restrict__ up_dw_b,
    float* __restrict__ ws_dwu,   // (N, 32, H, W)
    float* __restrict__ ws_ksa)   // (N, 25, H, W)
{
    __shared__ float tile[TILE_ELEMS];

    const int tid = threadIdx.x;
    const int tx = tid & (TW - 1);
    const int ty = tid >> 5;
    const int tile_x = blockIdx.x * TW;
    const int tile_y = blockIdx.y * TH;
    const int n = blockIdx.z;
    const int x = tile_x + tx, y = tile_y + ty;
    const int pix = y * IMW + x;

    const float* upb = upper + (size_t)n * NCH * HW;
    float* dwu_out = ws_dwu + (size_t)n * NCH * HW + pix;

    float dwu_ksa[NCH];

    #pragma unroll
    for (int ck = 0; ck < NCHUNK; ++ck) {
        const int c0 = ck * CHUNK;
        __syncthreads();
        for (int idx = tid; idx < TILE_ELEMS; idx += 256) {
            int c = idx / (HALO_H * HALO_W);
            int r = idx - c * (HALO_H * HALO_W);
            int hy = r / HALO_W, hx = r - hy * HALO_W;
            int gy = tile_y + hy - 2, gx = tile_x + hx - 2;
            float v = 0.0f;
            if (gy >= 0 && gy < IMH && gx >= 0 && gx < IMW)
                v = upb[(size_t)(c0 + c) * HW + gy * IMW + gx];
            tile[idx] = v;
        }
        __syncthreads();
        #pragma unroll
        for (int cc = 0; cc < CHUNK; ++cc) {
            const int c = c0 + cc;
            float ak = ksa_dw_b[c];
            float au = up_dw_b[c];
            const float* tp = tile + cc * (HALO_H * HALO_W) + ty * HALO_W + tx;
            #pragma unroll
            for (int i = 0; i < KS; ++i)
                #pragma unroll
                for (int j = 0; j < KS; ++j) {
                    float wv = tp[i * HALO_W + j];
                    ak = fmaf(wv, ksa_dw_w[c * 25 + i * KS + j], ak);
                    au = fmaf(wv, up_dw_w[c * 25 + i * KS + j], au);
                }
            dwu_ksa[c] = fmaxf(ak, 0.0f);
            dwu_out[(size_t)c * HW] = au;
        }
    }

    // KSA MLP: 32 -> 50 (relu) -> 25 (sigmoid)
    float ksa[25];
    #pragma unroll
    for (int k = 0; k < 25; ++k) ksa[k] = ksa_m2_b[k];
    for (int h = 0; h < 50; ++h) {
        float hv = ksa_m1_b[h];
        #pragma unroll
        for (int c = 0; c < NCH; ++c)
            hv = fmaf(ksa_m1_w[h * NCH + c], dwu_ksa[c], hv);
        hv = fmaxf(hv, 0.0f);
        #pragma unroll
        for (int k = 0; k < 25; ++k)
            ksa[k] = fmaf(ksa_m2_w[k * 50 + h], hv, ksa[k]);
    }

    float* ksa_out = ws_ksa + (size_t)n * 25 * HW + pix;
    #pragma unroll
    for (int k = 0; k < 25; ++k)
        ksa_out[(size_t)k * HW] = sigmoidf_(ksa[k]);
}

// ---------------------------------------------------------------------------
// Kernel B: lower pass streams dwl/td into LDS (bf16, per-thread columns, no
// barriers needed for them); pointwise/MLP phases stream back from LDS with
// only 8-wide register accumulators. Peak live regs ~70 floats.
// ---------------------------------------------------------------------------
__global__ __launch_bounds__(256) void cika_low_up_kernel(
    const float* __restrict__ lower,
    const float* __restrict__ ws_ksa, const float* __restrict__ ws_dwu,
    const float* __restrict__ kca_dw_w, const float* __restrict__ kca_dw_b,
    const float* __restrict__ kca_m1_w, const float* __restrict__ kca_m1_b,
    const float* __restrict__ kca_m2_w, const float* __restrict__ kca_m2_b,
    const float* __restrict__ low_dyn_w, const float* __restrict__ low_dyn_b,
    const float* __restrict__ low_pw_w, const float* __restrict__ low_pw_b,
    const float* __restrict__ up_pw_w, const float* __restrict__ up_pw_b,
    float* __restrict__ out_low, float* __restrict__ out_up)
{
    __shared__ float tile[TILE_ELEMS];
    __shared__ __hip_bfloat16 td_lds[NCH][256];   // dynamic-dw result
    __shared__ __hip_bfloat16 dwl_lds[NCH][256];  // relu(kca-dw) result

    const int tid = threadIdx.x;
    const int tx = tid & (TW - 1);
    const int ty = tid >> 5;
    const int tile_x = blockIdx.x * TW;
    const int tile_y = blockIdx.y * TH;
    const int n = blockIdx.z;
    const int x = tile_x + tx, y = tile_y + ty;
    const int pix = y * IMW + x;

    const float* lob = lower + (size_t)n * NCH * HW;

    // ksa attention weights for this pixel (live through phase 2 only)
    float ksa[25];
    {
        const float* kp = ws_ksa + (size_t)n * 25 * HW + pix;
        #pragma unroll
        for (int k = 0; k < 25; ++k) ksa[k] = kp[(size_t)k * HW];
    }

    // ---- Phase 2: lower pass; results go straight to LDS ----
    #pragma unroll
    for (int ck = 0; ck < NCHUNK; ++ck) {
        const int c0 = ck * CHUNK;
        __syncthreads();
        for (int idx = tid; idx < TILE_ELEMS; idx += 256) {
            int c = idx / (HALO_H * HALO_W);
            int r = idx - c * (HALO_H * HALO_W);
            int hy = r / HALO_W, hx = r - hy * HALO_W;
            int gy = tile_y + hy - 2, gx = tile_x + hx - 2;
            float v = 0.0f;
            if (gy >= 0 && gy < IMH && gx >= 0 && gx < IMW)
                v = lob[(size_t)(c0 + c) * HW + gy * IMW + gx];
            tile[idx] = v;
        }
        __syncthreads();
        #pragma unroll
        for (int cc = 0; cc < CHUNK; ++cc) {
            const int c = c0 + cc;
            float ad = kca_dw_b[c];
            float td = low_dyn_b[c];
            const float* tp = tile + cc * (HALO_H * HALO_W) + ty * HALO_W + tx;
            #pragma unroll
            for (int i = 0; i < KS; ++i)
                #pragma unroll
                for (int j = 0; j < KS; ++j) {
                    float wv = tp[i * HALO_W + j];
                    ad = fmaf(wv, kca_dw_w[c * 25 + i * KS + j], ad);
                    td = fmaf(wv * low_dyn_w[c * 25 + i * KS + j], ksa[i * KS + j], td);
                }
            dwl_lds[c][tid] = __float2bfloat16(fmaxf(ad, 0.0f));
            td_lds[c][tid]  = __float2bfloat16(td);
        }
    }
    // td_lds/dwl_lds are written and read only by column [.][tid] -> no barrier.

    // ---- Phase 3: out_low pointwise, chunked over output channels ----
    {
        float* ol = out_low + (size_t)n * NCH * HW + pix;
        #pragma unroll
        for (int oc = 0; oc < NCH / OC_CHUNK; ++oc) {
            float acc[OC_CHUNK];
            #pragma unroll
            for (int oo = 0; oo < OC_CHUNK; ++oo)
                acc[oo] = low_pw_b[oc * OC_CHUNK + oo];
            #pragma unroll
            for (int c = 0; c < NCH; ++c) {
                float v = __bfloat162float(td_lds[c][tid]);
                #pragma unroll
                for (int oo = 0; oo < OC_CHUNK; ++oo)
                    acc[oo] = fmaf(low_pw_w[(oc * OC_CHUNK + oo) * NCH + c], v, acc[oo]);
            }
            #pragma unroll
            for (int oo = 0; oo < OC_CHUNK; ++oo)
                ol[(size_t)(oc * OC_CHUNK + oo) * HW] = acc[oo];
        }
    }

    // ---- Phase 4: KCA MLP (stream dwl from LDS) ----
    float kca[NCH];
    {
        float hv[8];
        #pragma unroll
        for (int h = 0; h < 8; ++h) hv[h] = kca_m1_b[h];
        #pragma unroll
        for (int c = 0; c < NCH; ++c) {
            float v = __bfloat162float(dwl_lds[c][tid]);
            #pragma unroll
            for (int h = 0; h < 8; ++h)
                hv[h] = fmaf(kca_m1_w[h * NCH + c], v, hv[h]);
        }
        #pragma unroll
        for (int h = 0; h < 8; ++h) hv[h] = fmaxf(hv[h], 0.0f);
        #pragma unroll
        for (int k = 0; k < NCH; ++k) {
            float a = kca_m2_b[k];
            #pragma unroll
            for (int h = 0; h < 8; ++h)
                a = fmaf(kca_m2_w[k * 8 + h], hv[h], a);
            kca[k] = sigmoidf_(a);
        }
    }

    // ---- Phase 5: up path: gate dwu by kca, chunked pointwise ----
    float t2[NCH];
    {
        const float* dup = ws_dwu + (size_t)n * NCH * HW + pix;
        #pragma unroll
        for (int c = 0; c < NCH; ++c)
            t2[c] = dup[(size_t)c * HW] * kca[c];
    }
    {
        float* ou = out_up + (size_t)n * NCH * HW + pix;
        #pragma unroll
        for (int oc = 0; oc < NCH / OC_CHUNK; ++oc) {
            float acc[OC_CHUNK];
            #pragma unroll
            for (int oo = 0; oo < OC_CHUNK; ++oo)
                acc[oo] = up_pw_b[oc * OC_CHUNK + oo];
            #pragma unroll
            for (int c = 0; c < NCH; ++c) {
                #pragma unroll
                for (int oo = 0; oo < OC_CHUNK; ++oo)
                    acc[oo] = fmaf(up_pw_w[(oc * OC_CHUNK + oo) * NCH + c], t2[c], acc[oo]);
            }
            #pragma unroll
            for (int oo = 0; oo < OC_CHUNK; ++oo)
                ou[(size_t)(oc * OC_CHUNK + oo) * HW] = acc[oo];
        }
    }
}

extern "C" void kernel_launch(void* const* d_in, const int* in_sizes, int n_in,
                              void* d_out, int out_size, void* d_ws, size_t ws_size,
                              hipStream_t stream) {
    const float* lower    = (const float*)d_in[0];
    const float* upper    = (const float*)d_in[1];
    const float* kca_dw_w = (const float*)d_in[2];
    const float* kca_dw_b = (const float*)d_in[3];
    const float* kca_m1_w = (const float*)d_in[4];
    const float* kca_m1_b = (const float*)d_in[5];
    const float* kca_m2_w = (const float*)d_in[6];
    const float* kca_m2_b = (const float*)d_in[7];
    const float* ksa_dw_w = (const float*)d_in[8];
    const float* ksa_dw_b = (const float*)d_in[9];
    const float* ksa_m1_w = (const float*)d_in[10];
    const float* ksa_m1_b = (const float*)d_in[11];
    const float* ksa_m2_w = (const float*)d_in[12];
    const float* ksa_m2_b = (const float*)d_in[13];
    const float* low_dyn_w = (const float*)d_in[14];
    const float* low_dyn_b = (const float*)d_in[15];
    const float* low_pw_w  = (const float*)d_in[16];
    const float* low_pw_b  = (const float*)d_in[17];
    const float* up_dw_w   = (const float*)d_in[18];
    const float* up_dw_b   = (const float*)d_in[19];
    const float* up_pw_w   = (const float*)d_in[20];
    const float* up_pw_b   = (const float*)d_in[21];

    const int N = in_sizes[0] / (NCH * HW);
    float* out_low = (float*)d_out;
    float* out_up  = (float*)d_out + (size_t)N * NCH * HW;

    float* ws_dwu = (float*)d_ws;                       // N*32*HW floats
    float* ws_ksa = ws_dwu + (size_t)N * NCH * HW;      // N*25*HW floats

    dim3 grid(IMW / TW, IMH / TH, N);

    cika_ksa_kernel<<<grid, dim3(256), 0, stream>>>(
        upper,
        ksa_dw_w, ksa_dw_b, ksa_m1_w, ksa_m1_b, ksa_m2_w, ksa_m2_b,
        up_dw_w, up_dw_b,
        ws_dwu, ws_ksa);

    cika_low_up_kernel<<<grid, dim3(256), 0, stream>>>(
        lower, ws_ksa, ws_dwu,
        kca_dw_w, kca_dw_b, kca_m1_w, kca_m1_b, kca_m2_w, kca_m2_b,
        low_dyn_w, low_dyn_b, low_pw_w, low_pw_b,
        up_pw_w, up_pw_b,
        out_low, out_up);
}